// Round 1
// baseline (239.270 us; speedup 1.0000x reference)
//
#include <hip/hip_runtime.h>

#define LOG2E 1.4426950408889634f
#define LN2   0.6931471805599453f

constexpr int BB = 4096;
constexpr int S  = 512;
constexpr int NT = 9;
constexpr int TD = 11;

// One block = 256 threads = 16 groups of 16 lanes; one group per batch row.
// Phase A: real path score + length (all 16 lanes, strided over t, pipelined).
// Phase B: forward scan in log2 domain; lane j owns alpha[j] (j<9).
__global__ __launch_bounds__(256) void crf_fused(
    const float* __restrict__ em,    // [B][S][9]
    const int*   __restrict__ mask,  // [B][S]
    const int*   __restrict__ tags,  // [B][S]
    const float* __restrict__ trans, // [11][11]
    float* __restrict__ acc)         // acc[0] = sum(total - real), acc[1] = num_chars
{
    __shared__ float s_val[16];
    __shared__ float s_n[16];

    const int tid = threadIdx.x;
    const int g   = tid >> 4;
    const int k   = tid & 15;
    const int b   = blockIdx.x * 16 + g;

    const float* emB   = em + (size_t)b * (S * NT);
    const int*   maskB = mask + b * S;
    const int*   tagsB = tags + b * S;

    // ---------------- Phase A: real score + length ----------------
    float sumE = 0.f;
    int   cnt  = 0;

    int t  = k;
    int mk = maskB[t];
    int tg = tagsB[t];
    int prevcarry = 0;

    // 2-stage software pipeline: gathers issued in iter i, consumed in iter i+1
    float p_gv = 0.f, p_tr = 0.f;
    int   p_mk = 0;

    for (int i = 0; i < S / 16; ++i) {
        int mk2 = 0, tg2 = 0;
        if (i + 1 < S / 16) {           // prefetch next round's mask/tags
            mk2 = maskB[t + 16];
            tg2 = tagsB[t + 16];
        }
        float gv  = emB[t * NT + tg];   // emission gather (always safe)
        int   tgp = __shfl_up(tg, 1, 16);
        if (k == 0) tgp = prevcarry;    // tags[t-1] across round boundary
        float tr  = (t > 0) ? trans[tgp * TD + tg] : 0.f;
        prevcarry = __shfl(tg, 15, 16);

        if (p_mk) { sumE += p_gv + p_tr; cnt++; }   // consume previous
        p_gv = gv; p_tr = tr; p_mk = mk;

        mk = mk2; tg = tg2; t += 16;
    }
    if (p_mk) { sumE += p_gv + p_tr; cnt++; }       // drain

    #pragma unroll
    for (int d = 1; d < 16; d <<= 1) {
        sumE += __shfl_xor(sumE, d, 16);
        cnt  += __shfl_xor(cnt,  d, 16);
    }
    const int L = cnt;   // length of this batch (mask is a contiguous prefix)

    if (k == 0) {
        int tg0 = tagsB[0];
        int tgl = tagsB[L - 1];
        sumE += trans[9 * TD + tg0] + trans[tgl * TD + 10];  // first + last trans
        s_val[g] = -sumE;
        s_n[g]   = (float)L;
    }

    // ---------------- Phase B: forward scan ----------------
    int Lw = L;                                   // wave-max length (4 groups/wave)
    Lw = max(Lw, __shfl_xor(Lw, 16));
    Lw = max(Lw, __shfl_xor(Lw, 32));

    const bool active = (k < NT);
    const int  j = active ? k : 0;

    float w[NT];                                  // W[i][j] = 2^(T[i][j]*log2e)
    #pragma unroll
    for (int i = 0; i < NT; ++i)
        w[i] = exp2f(trans[i * TD + j] * LOG2E);

    float a = (trans[9 * TD + j] + emB[j]) * LOG2E;   // alpha0 in log2 units
    if (!active) a = -1e30f;
    float m = a;
    #pragma unroll
    for (int d = 1; d < 16; d <<= 1) m = fmaxf(m, __shfl_xor(m, d, 16));
    float e = active ? exp2f(a - m) : 0.f;

    float ldv = emB[NT + j];                      // prefetch em[b,1,j]

    for (int tt = 1; tt < Lw; ++tt) {
        float emc = ldv * LOG2E;
        if (tt + 1 < S) ldv = emB[(tt + 1) * NT + j];   // prefetch next step

        float e0 = __shfl(e, 0, 16);
        float e1 = __shfl(e, 1, 16);
        float e2 = __shfl(e, 2, 16);
        float e3 = __shfl(e, 3, 16);
        float e4 = __shfl(e, 4, 16);
        float e5 = __shfl(e, 5, 16);
        float e6 = __shfl(e, 6, 16);
        float e7 = __shfl(e, 7, 16);
        float e8 = __shfl(e, 8, 16);

        float d0 = e0 * w[0];
        d0 = fmaf(e1, w[1], d0);
        d0 = fmaf(e2, w[2], d0);
        float d1 = e3 * w[3];
        d1 = fmaf(e4, w[4], d1);
        d1 = fmaf(e5, w[5], d1);
        float d2 = e6 * w[6];
        d2 = fmaf(e7, w[7], d2);
        d2 = fmaf(e8, w[8], d2);
        float dot = (d0 + d1) + d2;

        float anew = emc + m + log2f(dot);
        if (active && tt < L) a = anew;           // masked update
        if ((tt & 3) == 0) m = __shfl(a, 0, 16);  // lagged proxy max refresh
        e = active ? exp2f(a - m) : 0.f;
    }

    // total = ln( sum_j exp(alpha_j + T[j,end]) )
    float v  = active ? (a + trans[j * TD + 10] * LOG2E) : -1e30f;
    float m2 = v;
    #pragma unroll
    for (int d = 1; d < 16; d <<= 1) m2 = fmaxf(m2, __shfl_xor(m2, d, 16));
    float sv = active ? exp2f(v - m2) : 0.f;
    #pragma unroll
    for (int d = 1; d < 16; d <<= 1) sv += __shfl_xor(sv, d, 16);

    if (k == 0) {
        float total = (m2 + log2f(sv)) * LN2;
        s_val[g] += total;                        // (total - real) for this batch
    }
    __syncthreads();
    if (tid == 0) {
        float vv = 0.f, nn = 0.f;
        #pragma unroll
        for (int q = 0; q < 16; ++q) { vv += s_val[q]; nn += s_n[q]; }
        atomicAdd(&acc[0], vv);
        atomicAdd(&acc[1], nn);
    }
}

__global__ void crf_final(const float* __restrict__ acc, float* __restrict__ out)
{
    out[0] = acc[0] / acc[1];
}

extern "C" void kernel_launch(void* const* d_in, const int* in_sizes, int n_in,
                              void* d_out, int out_size, void* d_ws, size_t ws_size,
                              hipStream_t stream) {
    const float* em    = (const float*)d_in[0];
    const int*   mask  = (const int*)d_in[1];
    const int*   tags  = (const int*)d_in[2];
    const float* trans = (const float*)d_in[3];
    float* acc = (float*)d_ws;

    hipMemsetAsync(acc, 0, 2 * sizeof(float), stream);
    crf_fused<<<BB / 16, 256, 0, stream>>>(em, mask, tags, trans, acc);
    crf_final<<<1, 1, 0, stream>>>(acc, (float*)d_out);
}

// Round 2
// 186.908 us; speedup vs baseline: 1.2801x; 1.2801x over previous
//
#include <hip/hip_runtime.h>

#define LOG2E 1.4426950408889634f
#define LN2   0.6931471805599453f

#if __has_builtin(__builtin_amdgcn_exp2f)
#define EXP2(x) __builtin_amdgcn_exp2f(x)
#else
#define EXP2(x) exp2f(x)
#endif
#if __has_builtin(__builtin_amdgcn_logf)
#define LOG2(x) __builtin_amdgcn_logf(x)
#else
#define LOG2(x) log2f(x)
#endif

constexpr int BB = 4096;
constexpr int S  = 512;
constexpr int NT = 9;
constexpr int TD = 11;
constexpr int PF = 16;   // emission prefetch depth (static register pipeline)

// One block = 256 threads = 16 groups of 16 lanes; one group per batch row.
// Phase A: real path score + length (all 16 lanes, strided over t, pipelined).
// Phase B: forward scan in log2 domain; lane j owns alpha[j] (j<9), with a
// PF-deep fully-unrolled emission prefetch so the serial chain is compute-
// latency bound instead of HBM-latency bound.
__global__ __launch_bounds__(256) void crf_fused(
    const float* __restrict__ em,    // [B][S][9]
    const int*   __restrict__ mask,  // [B][S]
    const int*   __restrict__ tags,  // [B][S]
    const float* __restrict__ trans, // [11][11]
    float* __restrict__ blkV,        // [gridDim] partial sum(total - real)
    float* __restrict__ blkN)        // [gridDim] partial num_chars
{
    __shared__ float s_val[16];
    __shared__ float s_n[16];

    const int tid = threadIdx.x;
    const int g   = tid >> 4;
    const int k   = tid & 15;
    const int b   = blockIdx.x * 16 + g;

    const float* emB   = em + (size_t)b * (S * NT);
    const int*   maskB = mask + b * S;
    const int*   tagsB = tags + b * S;

    // ---------------- Phase A: real score + length ----------------
    float sumE = 0.f;
    int   cnt  = 0;

    int t  = k;
    int mk = maskB[t];
    int tg = tagsB[t];
    int prevcarry = 0;

    float p_gv = 0.f, p_tr = 0.f;
    int   p_mk = 0;

    for (int i = 0; i < S / 16; ++i) {
        int mk2 = 0, tg2 = 0;
        if (i + 1 < S / 16) {
            mk2 = maskB[t + 16];
            tg2 = tagsB[t + 16];
        }
        float gv  = emB[t * NT + tg];
        int   tgp = __shfl_up(tg, 1, 16);
        if (k == 0) tgp = prevcarry;
        float tr  = (t > 0) ? trans[tgp * TD + tg] : 0.f;
        prevcarry = __shfl(tg, 15, 16);

        if (p_mk) { sumE += p_gv + p_tr; cnt++; }
        p_gv = gv; p_tr = tr; p_mk = mk;

        mk = mk2; tg = tg2; t += 16;
    }
    if (p_mk) { sumE += p_gv + p_tr; cnt++; }

    #pragma unroll
    for (int d = 1; d < 16; d <<= 1) {
        sumE += __shfl_xor(sumE, d, 16);
        cnt  += __shfl_xor(cnt,  d, 16);
    }
    const int L = cnt;

    if (k == 0) {
        int tg0 = tagsB[0];
        int tgl = tagsB[L - 1];
        sumE += trans[9 * TD + tg0] + trans[tgl * TD + 10];
        s_val[g] = -sumE;
        s_n[g]   = (float)L;
    }

    // ---------------- Phase B: forward scan ----------------
    int Lw = L;                                   // wave-max length
    Lw = max(Lw, __shfl_xor(Lw, 16));
    Lw = max(Lw, __shfl_xor(Lw, 32));

    const bool active = (k < NT);
    const int  j = active ? k : 0;

    float w[NT];                                  // W[i][j] = 2^(T[i][j]*log2e)
    #pragma unroll
    for (int i = 0; i < NT; ++i)
        w[i] = EXP2(trans[i * TD + j] * LOG2E);

    float a = (trans[9 * TD + j] + emB[j]) * LOG2E;   // alpha0 (log2 units)
    if (!active) a = -1e30f;
    float m = a;
    #pragma unroll
    for (int d = 1; d < 16; d <<= 1) m = fmaxf(m, __shfl_xor(m, d, 16));
    float e = active ? EXP2(a - m) : 0.f;

    // prime the PF-deep emission pipeline (steps 1..PF)
    float pf[PF];
    #pragma unroll
    for (int i = 0; i < PF; ++i) {
        int tt  = 1 + i;
        int idx = tt < S ? tt : S - 1;
        pf[i] = emB[idx * NT + j];
    }

    for (int base = 1; base < Lw; base += PF) {
        float nx[PF];
        #pragma unroll
        for (int i = 0; i < PF; ++i) {            // issue next chunk's loads
            int tt  = base + PF + i;
            int idx = tt < S ? tt : S - 1;
            nx[i] = emB[idx * NT + j];
        }
        #pragma unroll
        for (int i = 0; i < PF; ++i) {            // PF scan steps
            const int tt = base + i;
            float emc = pf[i] * LOG2E;

            float e0 = __shfl(e, 0, 16);
            float e1 = __shfl(e, 1, 16);
            float e2 = __shfl(e, 2, 16);
            float e3 = __shfl(e, 3, 16);
            float e4 = __shfl(e, 4, 16);
            float e5 = __shfl(e, 5, 16);
            float e6 = __shfl(e, 6, 16);
            float e7 = __shfl(e, 7, 16);
            float e8 = __shfl(e, 8, 16);

            float d0 = e0 * w[0];
            d0 = fmaf(e1, w[1], d0);
            d0 = fmaf(e2, w[2], d0);
            float d1 = e3 * w[3];
            d1 = fmaf(e4, w[4], d1);
            d1 = fmaf(e5, w[5], d1);
            float d2 = e6 * w[6];
            d2 = fmaf(e7, w[7], d2);
            d2 = fmaf(e8, w[8], d2);
            float dot = (d0 + d1) + d2;

            float anew = emc + m + LOG2(dot);
            if (active && tt < L) a = anew;
            if ((i & 3) == 3) m = m + LOG2(e0);   // proxy-max refresh (== a0_prev)
            e = active ? EXP2(a - m) : 0.f;
        }
        #pragma unroll
        for (int i = 0; i < PF; ++i) pf[i] = nx[i];
    }

    // total = ln( sum_j exp(alpha_j + T[j,end]) )
    float v  = active ? (a + trans[j * TD + 10] * LOG2E) : -1e30f;
    float m2 = v;
    #pragma unroll
    for (int d = 1; d < 16; d <<= 1) m2 = fmaxf(m2, __shfl_xor(m2, d, 16));
    float sv = active ? EXP2(v - m2) : 0.f;
    #pragma unroll
    for (int d = 1; d < 16; d <<= 1) sv += __shfl_xor(sv, d, 16);

    if (k == 0) {
        float total = (m2 + LOG2(sv)) * LN2;
        s_val[g] += total;
    }
    __syncthreads();
    if (tid == 0) {
        float vv = 0.f, nn = 0.f;
        #pragma unroll
        for (int q = 0; q < 16; ++q) { vv += s_val[q]; nn += s_n[q]; }
        blkV[blockIdx.x] = vv;
        blkN[blockIdx.x] = nn;
    }
}

// Reduce 256 per-block partials and divide. One block of 256 threads.
__global__ __launch_bounds__(256) void crf_final(
    const float* __restrict__ blkV,
    const float* __restrict__ blkN,
    float* __restrict__ out)
{
    const int tid = threadIdx.x;
    float v = blkV[tid];
    float n = blkN[tid];
    #pragma unroll
    for (int d = 1; d < 64; d <<= 1) {
        v += __shfl_xor(v, d);
        n += __shfl_xor(n, d);
    }
    __shared__ float sv[4], sn[4];
    if ((tid & 63) == 0) { sv[tid >> 6] = v; sn[tid >> 6] = n; }
    __syncthreads();
    if (tid == 0) {
        float vv = sv[0] + sv[1] + sv[2] + sv[3];
        float nn = sn[0] + sn[1] + sn[2] + sn[3];
        out[0] = vv / nn;
    }
}

extern "C" void kernel_launch(void* const* d_in, const int* in_sizes, int n_in,
                              void* d_out, int out_size, void* d_ws, size_t ws_size,
                              hipStream_t stream) {
    const float* em    = (const float*)d_in[0];
    const int*   mask  = (const int*)d_in[1];
    const int*   tags  = (const int*)d_in[2];
    const float* trans = (const float*)d_in[3];
    float* blkV = (float*)d_ws;            // 256 floats
    float* blkN = blkV + 256;              // 256 floats

    crf_fused<<<BB / 16, 256, 0, stream>>>(em, mask, tags, trans, blkV, blkN);
    crf_final<<<1, 256, 0, stream>>>(blkV, blkN, (float*)d_out);
}